// Round 3
// baseline (128.005 us; speedup 1.0000x reference)
//
#include <hip/hip_runtime.h>

// KAN layer as one fused fp16 MFMA GEMM:
//   out[b,i] = sum_j [ neg*bw*pw + pos*bw + sum_k basis[b,j,k]*sw[i,j]*sc[i,j,k] ]
// A  [2048 x 11264] fp16 : per j, 22 slots = {20 basis (5 nonzero), neg, pos}
// Ct [ 512 x 11264] fp16 : per j, 22 slots = {sw*sc[0..19], bw*pw, bw}   (B^T layout)
// R7: full 8-phase-schedule port (m201 template). R6 post-mortem: gemm sat at
//     590 TF-equiv == the 2-phase structural ceiling (m233: 607 TF) — NOT
//     operand-BW-bound (XCD pin was neutral). New gemm: 256x128 tile, grid
//     (8,4,8)=256 blocks = exactly 1/CU, 512 thr (8 waves, wave-tile 128x32),
//     BK=64, 3 single-K-step LDS buffers (144 KB), stage stream 2 tiles ahead,
//     4 phases/K-step: {ds_read frags || issue 1-2 global_load_lds -> barrier
//     -> setprio+8 MFMA -> barrier}, ONE counted vmcnt(6) per K-step (never 0
//     until the last tile). XOR-quad LDS swizzle on both sides (write via
//     pre-swizzled global source, read via swizzled ds_read) -> <=2-way banks.
// R5/R6 carried: KSPLIT=8 non-atomic partials + reduce8 (atomics killed);
//     XCD pin z = lid%8 (each XCD owns one k-split's operand slices).
// ws usage: A = 46.1 MB, Ct = 11.5 MB, partials = 33.6 MB (91.2 MB total).

typedef _Float16 half_t;
typedef __attribute__((ext_vector_type(8))) _Float16 half8;
typedef __attribute__((ext_vector_type(4))) float floatx4;

#define B_DIM   2048
#define J_DIM   512
#define O_DIM   512
#define SLOTS   22
#define K_TOT   (J_DIM * SLOTS)      // 11264
#define BM      256
#define BN      128
#define BK      64
#define KSPLIT_P 8                   // == NXCD, one z per XCD

// ---------------------------------------------------------------------------
// Quartic B-spline local basis, uniform knots g_i = -1.5 + i*(3.125/24).
// (Reference quirk: linspace(-1.5, 1.625, 25) -> spacing 3.125/24, NOT 0.125.)
// m in [3,19]; window k = m-4 .. m, entries with k<0 dropped.
__device__ __forceinline__ void bspline5(float xc, int& k0, float Nv[5]) {
    const float invS = 7.68f;              // 24/3.125 (exact ratio)
    float u = (xc + 1.5f) * invS;          // knot units
    int m = (int)u;
    m = min(max(m, 3), 19);
    k0 = m - 4;
    Nv[0] = 1.f; Nv[1] = 0.f; Nv[2] = 0.f; Nv[3] = 0.f; Nv[4] = 0.f;
#pragma unroll
    for (int d = 1; d <= 4; ++d) {
        float nw[5];
        float inv_d = 1.0f / (float)d;
#pragma unroll
        for (int r = 0; r < 5; ++r) {
            if (r > d) { nw[r] = 0.f; continue; }
            float kk = (float)(m - d + r);
            float acc = 0.f;
            if (r >= 1) acc += (u - kk) * Nv[r - 1];
            if (r < d)  acc += (kk + (float)(d + 1) - u) * Nv[r];
            nw[r] = acc * inv_d;
        }
#pragma unroll
        for (int r = 0; r < 5; ++r) Nv[r] = nw[r];
    }
}

// ---------------------------------------------------------------------------
// Fused prep: blocks [0,512) build Ct rows; [512, 512+2048) build A rows.
__global__ __launch_bounds__(256) void prep_all(const float* __restrict__ x,
                                                const float* __restrict__ pw,
                                                const float* __restrict__ bw,
                                                const float* __restrict__ sw,
                                                const float* __restrict__ sc,
                                                half_t* __restrict__ A,
                                                half_t* __restrict__ Ct) {
    __shared__ half_t rec[J_DIM * SLOTS];  // 22528 B
    int bid = blockIdx.x;
    int t = threadIdx.x;

    if (bid < O_DIM) {
        // prep_C: fold spline_weight into coeffs + base slots. sc row is
        // 16B-aligned per (i,j): ij*20 floats = ij*80 B.
        int i = bid;
#pragma unroll
        for (int jj = 0; jj < 2; ++jj) {
            int j = t + jj * 256;
            size_t ij = (size_t)i * J_DIM + j;
            float s = sw[ij], b = bw[ij], p = pw[ij];
            const float4* scp4 = (const float4*)(sc + ij * 20);
            half_t* r = rec + j * SLOTS;
#pragma unroll
            for (int v = 0; v < 5; ++v) {
                float4 c4 = scp4[v];
                r[v * 4 + 0] = (half_t)(s * c4.x);
                r[v * 4 + 1] = (half_t)(s * c4.y);
                r[v * 4 + 2] = (half_t)(s * c4.z);
                r[v * 4 + 3] = (half_t)(s * c4.w);
            }
            r[20] = (half_t)(b * p);
            r[21] = (half_t)b;
        }
        __syncthreads();
        const uint4* src = (const uint4*)rec;
        uint4* dst = (uint4*)(Ct + (size_t)i * K_TOT);
        for (int idx = t; idx < (J_DIM * SLOTS * 2) / 16; idx += 256) dst[idx] = src[idx];
        return;
    }

    // prep_A: basis record per (b, j)
    int b = bid - O_DIM;
#pragma unroll
    for (int jj = 0; jj < 2; ++jj) {
        int j = t + jj * 256;
        float xv = x[(size_t)b * J_DIM + j];
        float xc = fminf(fmaxf(xv, -1.f), 1.f);
        float pos = fmaxf(xc, 0.f);
        float neg = xc - pos;
        int k0; float Nv[5];
        bspline5(xc, k0, Nv);
        half_t* r = rec + j * SLOTS;
#pragma unroll
        for (int k = 0; k < 20; ++k) r[k] = (half_t)0.f;
#pragma unroll
        for (int rr = 0; rr < 5; ++rr) {
            int k = k0 + rr;
            if (k >= 0) r[k] = (half_t)Nv[rr];   // k <= 19 guaranteed (k0 <= 15)
        }
        r[20] = (half_t)neg;
        r[21] = (half_t)pos;
    }
    __syncthreads();
    const uint4* src = (const uint4*)rec;
    uint4* dst = (uint4*)(A + (size_t)b * K_TOT);
    for (int i = t; i < (J_DIM * SLOTS * 2) / 16; i += 256) dst[i] = src[i];
}

// ---------------------------------------------------------------------------
// 8-phase GEMM. Grid (8,4,8)=256 blocks (1/CU), 512 thr = 8 waves (2m x 4n),
// wave-tile 128x32, acc[8][2]. Per K-step (BK=64): 4 phases, each
//   { ds_read frags ; issue stage loads (tile T+2) ; barrier ;
//     setprio(1) 8x MFMA setprio(0) ; barrier }
// Tile-ready guard at loop top: s_waitcnt vmcnt(6) (tile T landed, tile T+1's
// 6 loads still flying) + barrier. vmcnt drains to 0 only at the final tile.
// LDS: 3 single-K-step buffers (A 32 KB + B 16 KB each) = 144 KB.
// Swizzle: LDS[row][quad d] = G[row][d ^ (row&7)] (quad = 16 B), applied via
// pre-swizzled global source (write side, linear LDS dest for global_load_lds)
// and XOR'd ds_read offset (read side). Bank aliasing <= 2-way (free, m136).
__global__ __launch_bounds__(512, 2) void gemm8_f16(const half_t* __restrict__ A,
                                                    const half_t* __restrict__ Bt,
                                                    float* __restrict__ out) {
    constexpr int KS_LEN = K_TOT / KSPLIT_P;   // 1408
    constexpr int NSTEP = KS_LEN / BK;         // 22 (even)

    __shared__ half_t As[3][BM * BK];   // 3 x 32 KB
    __shared__ half_t Bs[3][BN * BK];   // 3 x 16 KB

    // XCD pin: linear dispatch id % 8 selects XCD; give each XCD one k-split.
    int lid = blockIdx.x + 8 * (blockIdx.y + 4 * blockIdx.z);   // 0..255
    int bz = lid & 7;
    int rem = lid >> 3;          // 0..31
    int bx = rem & 7;            // 8 m-blocks
    int by = rem >> 3;           // 4 n-blocks

    int m0 = bx * BM, n0 = by * BN, ks = bz * KS_LEN;

    int t = threadIdx.x;
    int w = t >> 6, l = t & 63;
    int wm = w >> 2, wn = w & 3;          // wave grid 2 x 4
    int q = l >> 4, fr = l & 15;          // MFMA fragment coords

    const half_t* gA = A + (size_t)m0 * K_TOT + ks;
    const half_t* gB = Bt + (size_t)n0 * K_TOT + ks;

    // staging lane decomposition: 8 rows x 8 quads per wave-instruction (1 KB)
    int srow = l >> 3;                    // 0..7 row within 8-row group
    int sqsw = ((l & 7) ^ srow) * 8;      // pre-swizzled source quad (halfs)

    // read-side swizzled k-offsets (halfs) for ksub 0/1 of a BK=64 row
    int fsw0 = ((q)     ^ (fr & 7)) * 8;
    int fsw1 = ((4 + q) ^ (fr & 7)) * 8;

    floatx4 acc[8][2] = {};

#define STAGE_A(kb, p, s)                                                     \
    __builtin_amdgcn_global_load_lds(                                         \
        (const __attribute__((address_space(1))) unsigned int*)               \
            (gA + (size_t)((s) * 64 + w * 8 + srow) * K_TOT + (kb) + sqsw),   \
        (__attribute__((address_space(3))) unsigned int*)                     \
            (&As[p][((s) * 64 + w * 8) * BK]),                                \
        16, 0, 0);
#define STAGE_B(kb, p, s)                                                     \
    __builtin_amdgcn_global_load_lds(                                         \
        (const __attribute__((address_space(1))) unsigned int*)               \
            (gB + (size_t)((s) * 64 + w * 8 + srow) * K_TOT + (kb) + sqsw),   \
        (__attribute__((address_space(3))) unsigned int*)                     \
            (&Bs[p][((s) * 64 + w * 8) * BK]),                                \
        16, 0, 0);
// per-wave per-tile FIFO order: A s0,s1,s2,s3 then B s0,s1  (6 loads)

    // prologue: stage tiles 0 and 1
    STAGE_A(0, 0, 0) STAGE_A(0, 0, 1) STAGE_A(0, 0, 2) STAGE_A(0, 0, 3)
    STAGE_B(0, 0, 0) STAGE_B(0, 0, 1)
    STAGE_A(BK, 1, 0) STAGE_A(BK, 1, 1) STAGE_A(BK, 1, 2) STAGE_A(BK, 1, 3)
    STAGE_B(BK, 1, 0) STAGE_B(BK, 1, 1)

#define AFRD(mt, kss) (*(const half8*)(Ab + ((wm << 7) + ((mt) << 4) + fr) * BK + (kss)))
#define BFRD(nt, kss) (*(const half8*)(Bb + ((wn << 5) + ((nt) << 4) + fr) * BK + (kss)))
#define MM(mt, a0, a1)                                                            \
    acc[mt][0] = __builtin_amdgcn_mfma_f32_16x16x32_f16(a0, bfr00, acc[mt][0], 0, 0, 0); \
    acc[mt][0] = __builtin_amdgcn_mfma_f32_16x16x32_f16(a1, bfr01, acc[mt][0], 0, 0, 0); \
    acc[mt][1] = __builtin_amdgcn_mfma_f32_16x16x32_f16(a0, bfr10, acc[mt][1], 0, 0, 0); \
    acc[mt][1] = __builtin_amdgcn_mfma_f32_16x16x32_f16(a1, bfr11, acc[mt][1], 0, 0, 0);

    int cb = 0;
    for (int T = 0; T < NSTEP; ++T) {
        // tile-ready guard: my 6 loads for tile T are the oldest outstanding
        if (T < NSTEP - 1) { asm volatile("s_waitcnt vmcnt(6)" ::: "memory"); }
        else               { asm volatile("s_waitcnt vmcnt(0)" ::: "memory"); }
        __builtin_amdgcn_s_barrier();

        const bool st = (T + 2 < NSTEP);
        int sb = cb + 2; if (sb >= 3) sb -= 3;
        const int kb = (T + 2) * BK;
        const half_t* Ab = &As[cb][0];
        const half_t* Bb = &Bs[cb][0];

        half8 a0, a1, a2, a3;

        // ---- phase 0: bf(all) + af(mt 0,1) ; stage A s0,s1 ; MFMA mt 0,1
        half8 bfr00 = BFRD(0, fsw0), bfr01 = BFRD(0, fsw1);
        half8 bfr10 = BFRD(1, fsw0), bfr11 = BFRD(1, fsw1);
        a0 = AFRD(0, fsw0); a1 = AFRD(0, fsw1);
        a2 = AFRD(1, fsw0); a3 = AFRD(1, fsw1);
        if (st) { STAGE_A(kb, sb, 0) STAGE_A(kb, sb, 1) }
        __builtin_amdgcn_s_barrier();
        __builtin_amdgcn_s_setprio(1);
        MM(0, a0, a1) MM(1, a2, a3)
        __builtin_amdgcn_s_setprio(0);
        __builtin_amdgcn_s_barrier();

        // ---- phase 1: af(mt 2,3) ; stage A s2,s3 ; MFMA mt 2,3
        a0 = AFRD(2, fsw0); a1 = AFRD(2, fsw1);
        a2 = AFRD(3, fsw0); a3 = AFRD(3, fsw1);
        if (st) { STAGE_A(kb, sb, 2) STAGE_A(kb, sb, 3) }
        __builtin_amdgcn_s_barrier();
        __builtin_amdgcn_s_setprio(1);
        MM(2, a0, a1) MM(3, a2, a3)
        __builtin_amdgcn_s_setprio(0);
        __builtin_amdgcn_s_barrier();

        // ---- phase 2: af(mt 4,5) ; stage B s0 ; MFMA mt 4,5
        a0 = AFRD(4, fsw0); a1 = AFRD(4, fsw1);
        a2 = AFRD(5, fsw0); a3 = AFRD(5, fsw1);
        if (st) { STAGE_B(kb, sb, 0) }
        __builtin_amdgcn_s_barrier();
        __builtin_amdgcn_s_setprio(1);
        MM(4, a0, a1) MM(5, a2, a3)
        __builtin_amdgcn_s_setprio(0);
        __builtin_amdgcn_s_barrier();

        // ---- phase 3: af(mt 6,7) ; stage B s1 ; MFMA mt 6,7
        // (closing barrier of this phase == next iteration's loop-top barrier)
        a0 = AFRD(6, fsw0); a1 = AFRD(6, fsw1);
        a2 = AFRD(7, fsw0); a3 = AFRD(7, fsw1);
        if (st) { STAGE_B(kb, sb, 1) }
        __builtin_amdgcn_s_barrier();
        __builtin_amdgcn_s_setprio(1);
        MM(6, a0, a1) MM(7, a2, a3)
        __builtin_amdgcn_s_setprio(0);

        if (++cb == 3) cb = 0;
    }
#undef MM
#undef AFRD
#undef BFRD
#undef STAGE_A
#undef STAGE_B

    // epilogue: C/D layout col = lane&15, row = (lane>>4)*4 + reg (m89-verified)
    float* dst = out + (size_t)bz * ((size_t)B_DIM * O_DIM);
#pragma unroll
    for (int mt = 0; mt < 8; ++mt)
#pragma unroll
        for (int nt = 0; nt < 2; ++nt) {
            int rr = m0 + wm * 128 + mt * 16 + q * 4;
            int cc = n0 + wn * 32 + nt * 16 + fr;
#pragma unroll
            for (int r = 0; r < 4; ++r)
                dst[(size_t)(rr + r) * O_DIM + cc] = acc[mt][nt][r];
        }
}

// ---------------------------------------------------------------------------
// Sum the KSPLIT_P partial buffers into out. 37.7 MB traffic, BW-bound.
__global__ __launch_bounds__(256) void reduce8(const float* __restrict__ parts,
                                               float* __restrict__ out) {
    constexpr int N4 = B_DIM * O_DIM / 4;
    int i = blockIdx.x * 256 + threadIdx.x;       // float4 index
    const float4* p = (const float4*)parts;
    float4 a = p[i];
#pragma unroll
    for (int z = 1; z < KSPLIT_P; ++z) {
        float4 b = p[(size_t)z * N4 + i];
        a.x += b.x; a.y += b.y; a.z += b.z; a.w += b.w;
    }
    ((float4*)out)[i] = a;
}

// ---------------------------------------------------------------------------
// Zero-workspace fallback (only if ws_size too small): correct but slow.
__global__ __launch_bounds__(256) void kan_fallback(const float* __restrict__ x,
                                                    const float* __restrict__ pw,
                                                    const float* __restrict__ bw,
                                                    const float* __restrict__ sw,
                                                    const float* __restrict__ sc,
                                                    float* __restrict__ out) {
    __shared__ float s_neg[J_DIM], s_pos[J_DIM], s_bas[J_DIM][5];
    __shared__ int s_k0[J_DIM];
    int b = blockIdx.x;
    int t = threadIdx.x;
#pragma unroll
    for (int jj = 0; jj < 2; ++jj) {
        int j = t + jj * 256;
        float xv = x[(size_t)b * J_DIM + j];
        float xc = fminf(fmaxf(xv, -1.f), 1.f);
        float pos = fmaxf(xc, 0.f);
        s_pos[j] = pos;
        s_neg[j] = xc - pos;
        int k0; float Nv[5];
        bspline5(xc, k0, Nv);
        s_k0[j] = k0;
#pragma unroll
        for (int r = 0; r < 5; ++r) s_bas[j][r] = Nv[r];
    }
    __syncthreads();
    for (int i = t; i < O_DIM; i += 256) {
        float acc = 0.f;
        for (int j = 0; j < J_DIM; ++j) {
            size_t ij = (size_t)i * J_DIM + j;
            float bwv = bw[ij];
            acc += bwv * (pw[ij] * s_neg[j] + s_pos[j]);
            int k0 = s_k0[j];
            const float* cp = sc + ij * 20;
            float sp = 0.f;
#pragma unroll
            for (int r = 0; r < 5; ++r) {
                int k = k0 + r;
                if (k >= 0) sp += s_bas[j][r] * cp[k];
            }
            acc += sw[ij] * sp;
        }
        out[(size_t)b * O_DIM + i] = acc;
    }
}

// ---------------------------------------------------------------------------
extern "C" void kernel_launch(void* const* d_in, const int* in_sizes, int n_in,
                              void* d_out, int out_size, void* d_ws, size_t ws_size,
                              hipStream_t stream) {
    const float* x  = (const float*)d_in[0];
    const float* pw = (const float*)d_in[1];
    const float* bw = (const float*)d_in[2];
    const float* sw = (const float*)d_in[3];
    const float* sc = (const float*)d_in[4];
    float* out = (float*)d_out;

    const size_t abct = (size_t)(B_DIM + O_DIM) * K_TOT * sizeof(half_t);        // 57.7 MB
    const size_t parts_bytes = (size_t)KSPLIT_P * B_DIM * O_DIM * sizeof(float); // 33.6 MB

    if (ws_size >= abct + parts_bytes) {
        half_t* A  = (half_t*)d_ws;
        half_t* Ct = A + (size_t)B_DIM * K_TOT;
        float* parts = (float*)((char*)d_ws + abct);   // 16B-aligned (abct % 16 == 0)

        prep_all<<<O_DIM + B_DIM, 256, 0, stream>>>(x, pw, bw, sw, sc, A, Ct);
        dim3 g(B_DIM / BM, O_DIM / BN, KSPLIT_P);      // (8, 4, 8)
        gemm8_f16<<<g, 512, 0, stream>>>(A, Ct, parts);
        reduce8<<<(B_DIM * O_DIM / 4) / 256, 256, 0, stream>>>(parts, out);
    } else {
        kan_fallback<<<B_DIM, 256, 0, stream>>>(x, pw, bw, sw, sc, out);
    }
}